// Round 6
// baseline (437.315 us; speedup 1.0000x reference)
//
#include <hip/hip_runtime.h>

#define D 128

typedef __attribute__((ext_vector_type(8))) short short8;
typedef __attribute__((ext_vector_type(4))) float f32x4;

// ---- bf16 pack helpers (round-to-nearest-even)
__device__ inline unsigned bfr(float f) {
  unsigned u = __float_as_uint(f);
  return (u + 0x7fffu + ((u >> 16) & 1u)) >> 16;
}
__device__ inline unsigned pack2(float lo, float hi) {
  return bfr(lo) | (bfr(hi) << 16);
}
__device__ inline float unpk_lo(unsigned v) { return __uint_as_float(v << 16); }
__device__ inline float unpk_hi(unsigned v) { return __uint_as_float(v & 0xffff0000u); }

// ---------------- W1 fp32 [k][n] -> bf16 transposed Wtg [n][k] (global, 32 KB)
__global__ __launch_bounds__(256) void k_wt(const float* __restrict__ W,
                                            unsigned short* __restrict__ Wtg) {
  int i = blockIdx.x * 256 + threadIdx.x;
  if (i < 128 * 128) {
    int k = i >> 7, n = i & 127;
    Wtg[n * 128 + k] = (unsigned short)bfr(W[k * 128 + n]);
  }
}

// ---------------- FUSED front: deg+rank (role A) || MFMA gemm h = x@W1 (role B)
// h stored as packed bf16x2, UNSCALED (dinv applied later in k_agg).
__global__ __launch_bounds__(256) void k_front(
    const float* __restrict__ x, const unsigned short* __restrict__ Wtg,
    const int* __restrict__ dst, int* __restrict__ deg, int* __restrict__ rank,
    unsigned* __restrict__ hu, int M, int E, int NDEG, int nChunks) {
  __shared__ unsigned short xs[64 * 136];  // 17.4 KB padded bf16 x-tile
  int b = blockIdx.x;
  int t = threadIdx.x;

  if (b < NDEG) {
    // ---- degree + rank role: rank[e] = old deg[dst[e]]++
    for (int c = b; c < nChunks; c += NDEG) {
      int i = c * 1024 + t * 4;
      if (i + 3 < E) {
        int4 d4 = *(const int4*)(dst + i);
        int4 r4;
        r4.x = atomicAdd(&deg[d4.x], 1);
        r4.y = atomicAdd(&deg[d4.y], 1);
        r4.z = atomicAdd(&deg[d4.z], 1);
        r4.w = atomicAdd(&deg[d4.w], 1);
        *(int4*)(rank + i) = r4;
      } else {
        for (int j = i; j < E; ++j) rank[j] = atomicAdd(&deg[dst[j]], 1);
      }
    }
    return;
  }

  // ---- MFMA gemm role: 64 rows x 128 cols per block
  int row0 = (b - NDEG) * 64;
  if (row0 >= M) return;

  for (int i = t; i < 2048; i += 256) {
    int r = i >> 5;
    int rg = row0 + r;
    int rc = rg < M ? rg : M - 1;
    float4 v = ((const float4*)x)[(size_t)rc * 32 + (i & 31)];
    *(uint2*)&xs[r * 136 + (i & 31) * 4] = make_uint2(pack2(v.x, v.y), pack2(v.z, v.w));
  }
  __syncthreads();

  int lane = t & 63;
  int wid = t >> 6;
  int l15 = lane & 15;
  int quad = lane >> 4;
  int mloc = wid * 16 + l15;

  f32x4 acc[8];
  #pragma unroll
  for (int ct = 0; ct < 8; ++ct) acc[ct] = (f32x4){0.f, 0.f, 0.f, 0.f};

  #pragma unroll
  for (int k0 = 0; k0 < 128; k0 += 32) {
    short8 af = *(const short8*)&xs[mloc * 136 + k0 + quad * 8];
    #pragma unroll
    for (int ct = 0; ct < 8; ++ct) {
      short8 bf = *(const short8*)(Wtg + (ct * 16 + l15) * 128 + k0 + quad * 8);
      acc[ct] = __builtin_amdgcn_mfma_f32_16x16x32_bf16(af, bf, acc[ct], 0, 0, 0);
    }
  }

  // epilogue: C/D layout col=lane&15, row=quad*4+reg; pack col pairs via shfl
  int rowbase = row0 + wid * 16 + quad * 4;
  #pragma unroll
  for (int ct = 0; ct < 8; ++ct) {
    #pragma unroll
    for (int r = 0; r < 4; ++r) {
      float v = acc[ct][r];
      float vp = __shfl_xor(v, 1, 64);
      int row = rowbase + r;
      if (!(lane & 1) && row < M)
        hu[(size_t)row * 64 + ct * 8 + (l15 >> 1)] = pack2(v, vp);
    }
  }
}

// ---------------- scan stage 1: per-block (1024 elems) sums
__global__ __launch_bounds__(256) void k_scan1(const int* __restrict__ deg,
                                               int* __restrict__ bsum, int N) {
  int t = threadIdx.x;
  int base = blockIdx.x * 1024;
  int s = 0;
  for (int i = t; i < 1024; i += 256) {
    int idx = base + i;
    if (idx < N) s += deg[idx];
  }
  __shared__ int red[256];
  red[t] = s;
  __syncthreads();
  for (int off = 128; off > 0; off >>= 1) {
    if (t < off) red[t] += red[t + off];
    __syncthreads();
  }
  if (t == 0) bsum[blockIdx.x] = red[0];
}

// ---------------- scan stage 2: parallel exclusive scan of block sums (nb <= 128)
__global__ __launch_bounds__(128) void k_scan2(int* __restrict__ bsum, int nb,
                                               int* __restrict__ offs, int N) {
  __shared__ int sc[128];
  int t = threadIdx.x;
  int v = (t < nb) ? bsum[t] : 0;
  sc[t] = v;
  __syncthreads();
  #pragma unroll
  for (int off = 1; off < 128; off <<= 1) {
    int x = (t >= off) ? sc[t - off] : 0;
    __syncthreads();
    sc[t] += x;
    __syncthreads();
  }
  if (t < nb) bsum[t] = sc[t] - v;
  if (t == nb - 1) offs[N] = sc[t];
}

// ---------------- scan stage 3: in-block exclusive scan -> offs; fused dinv
__global__ __launch_bounds__(256) void k_scan3(const int* __restrict__ deg,
                                               const int* __restrict__ bsum,
                                               int* __restrict__ offs,
                                               float* __restrict__ dinv, int N) {
  int t = threadIdx.x;
  int base = blockIdx.x * 1024 + t * 4;
  int v[4];
  int s = 0;
  #pragma unroll
  for (int j = 0; j < 4; ++j) {
    int idx = base + j;
    v[j] = (idx < N) ? deg[idx] : 0;
    s += v[j];
  }
  __shared__ int sc[256];
  sc[t] = s;
  __syncthreads();
  for (int off = 1; off < 256; off <<= 1) {
    int x = (t >= off) ? sc[t - off] : 0;
    __syncthreads();
    sc[t] += x;
    __syncthreads();
  }
  int p = bsum[blockIdx.x] + sc[t] - s;
  #pragma unroll
  for (int j = 0; j < 4; ++j) {
    int idx = base + j;
    if (idx < N) {
      offs[idx] = p;
      dinv[idx] = rsqrtf((float)v[j] + 1.0f);
      p += v[j];
    }
  }
}

// ---------------- fill: atomic-free CSR bucket write + ssum (full grid)
__global__ __launch_bounds__(256) void k_fill(
    const int* __restrict__ src, const int* __restrict__ dst,
    const int* __restrict__ rank, const int* __restrict__ offs,
    const float* __restrict__ dinv, int* __restrict__ bucket,
    float* __restrict__ ssum, int E) {
  int i = (blockIdx.x * 256 + threadIdx.x) * 4;
  if (i + 3 < E) {
    int4 s4 = *(const int4*)(src + i);
    int4 d4 = *(const int4*)(dst + i);
    int4 r4 = *(const int4*)(rank + i);
    bucket[offs[d4.x] + r4.x] = s4.x;
    bucket[offs[d4.y] + r4.y] = s4.y;
    bucket[offs[d4.z] + r4.z] = s4.z;
    bucket[offs[d4.w] + r4.w] = s4.w;
    unsafeAtomicAdd(&ssum[s4.x], dinv[d4.x]);
    unsafeAtomicAdd(&ssum[s4.y], dinv[d4.y]);
    unsafeAtomicAdd(&ssum[s4.z], dinv[d4.z]);
    unsafeAtomicAdd(&ssum[s4.w], dinv[d4.w]);
  } else {
    for (int j = i; j < E; ++j) {
      int s = src[j], d = dst[j];
      bucket[offs[d] + rank[j]] = s;
      unsafeAtomicAdd(&ssum[s], dinv[d]);
    }
  }
}

// ---------------- fused gather-aggregate + epilogue + weighted reduce
// h unscaled: ax = sum dinv[s]*h[s]; h1 = relu(di*(ax + di*h_r) + b1)
__global__ __launch_bounds__(256) void k_agg(const unsigned* __restrict__ hu,
                                             const int* __restrict__ bucket,
                                             const int* __restrict__ offs,
                                             const float* __restrict__ dinv,
                                             const float* __restrict__ ssum,
                                             const float* __restrict__ b1,
                                             float* __restrict__ vpart, int N) {
  int lane = threadIdx.x & 63;
  int wid = threadIdx.x >> 6;
  int gwave = blockIdx.x * 4 + wid;
  int nwave = gridDim.x * 4;
  float2 bb = *(const float2*)(b1 + lane * 2);
  float vx = 0.f, vy = 0.f;

  for (int r = gwave; r < N; r += nwave) {
    int beg = offs[r], end = offs[r + 1];
    float ax = 0.f, ay = 0.f;
    int j = beg;
    for (; j + 4 <= end; j += 4) {
      int s0 = bucket[j], s1 = bucket[j + 1], s2 = bucket[j + 2], s3 = bucket[j + 3];
      float e0 = dinv[s0], e1 = dinv[s1], e2 = dinv[s2], e3 = dinv[s3];
      unsigned v0 = hu[(size_t)s0 * 64 + lane];
      unsigned v1 = hu[(size_t)s1 * 64 + lane];
      unsigned v2 = hu[(size_t)s2 * 64 + lane];
      unsigned v3 = hu[(size_t)s3 * 64 + lane];
      ax = fmaf(e0, unpk_lo(v0), ax);
      ay = fmaf(e0, unpk_hi(v0), ay);
      ax = fmaf(e1, unpk_lo(v1), ax);
      ay = fmaf(e1, unpk_hi(v1), ay);
      ax = fmaf(e2, unpk_lo(v2), ax);
      ay = fmaf(e2, unpk_hi(v2), ay);
      ax = fmaf(e3, unpk_lo(v3), ax);
      ay = fmaf(e3, unpk_hi(v3), ay);
    }
    for (; j < end; ++j) {
      int s = bucket[j];
      float e = dinv[s];
      unsigned v = hu[(size_t)s * 64 + lane];
      ax = fmaf(e, unpk_lo(v), ax);
      ay = fmaf(e, unpk_hi(v), ay);
    }
    unsigned gr = hu[(size_t)r * 64 + lane];
    float di = dinv[r];
    float w = di * (ssum[r] + di);
    float hx = fmaxf(fmaf(di, fmaf(di, unpk_lo(gr), ax), bb.x), 0.f);
    float hy = fmaxf(fmaf(di, fmaf(di, unpk_hi(gr), ay), bb.y), 0.f);
    vx = fmaf(w, hx, vx);
    vy = fmaf(w, hy, vy);
  }

  __shared__ float2 red[256];
  red[threadIdx.x] = make_float2(vx, vy);
  __syncthreads();
  if (threadIdx.x < 64) {
    float2 a = red[threadIdx.x], b = red[threadIdx.x + 64];
    float2 c = red[threadIdx.x + 128], d = red[threadIdx.x + 192];
    float2 o = make_float2((a.x + b.x) + (c.x + d.x), (a.y + b.y) + (c.y + d.y));
    *(float2*)(vpart + (size_t)blockIdx.x * D + lane * 2) = o;
  }
}

// ---------------- final: v = sum partials; out = (1/N)*v@W2 + b2
__global__ __launch_bounds__(1024) void k_final(const float* __restrict__ vpart,
                                                int npart,
                                                const float* __restrict__ W2,
                                                const float* __restrict__ b2,
                                                float* __restrict__ out, float invN) {
  __shared__ float seg[8][128];
  __shared__ float vs[128];
  int t = threadIdx.x;
  int c = t & 127, sg = t >> 7;
  float s = 0.f;
  for (int b = sg; b < npart; b += 8) s += vpart[(size_t)b * D + c];
  seg[sg][c] = s;
  __syncthreads();
  if (t < 128) {
    float tot = 0.f;
    #pragma unroll
    for (int k = 0; k < 8; ++k) tot += seg[k][c];
    vs[c] = tot;
  }
  __syncthreads();
  if (t < 128) {
    float o = 0.f;
    for (int k = 0; k < 128; ++k) o = fmaf(vs[k], W2[k * D + c], o);
    out[c] = fmaf(o, invN, b2[c]);
  }
}

extern "C" void kernel_launch(void* const* d_in, const int* in_sizes, int n_in,
                              void* d_out, int out_size, void* d_ws, size_t ws_size,
                              hipStream_t stream) {
  const float* x  = (const float*)d_in[0];
  const int*   ei = (const int*)d_in[1];
  const float* W1 = (const float*)d_in[2];
  const float* b1 = (const float*)d_in[3];
  const float* W2 = (const float*)d_in[4];
  const float* b2 = (const float*)d_in[5];
  float* out = (float*)d_out;

  int N = in_sizes[0] / D;
  int E = in_sizes[1] / 2;
  const int* src = ei;
  const int* dst = ei + E;

  const int NB_SCAN = (N + 1023) / 1024;
  const int AGG_BLOCKS = 2048;
  const int nChunks = (E + 1023) / 1024;
  const int NDEG = (nChunks + 1) / 2;          // ~782 deg blocks, 2 chunks each
  const int NGEMM = (N + 63) / 64;

  char* p = (char*)d_ws;
  int*   deg    = (int*)p;        p += (size_t)N * 4;
  float* ssum   = (float*)p;      p += (size_t)N * 4;
  float* dinv   = (float*)p;      p += (size_t)N * 4;
  int*   offs   = (int*)p;        p += (size_t)(N + 1) * 4;
  int*   bsum   = (int*)p;        p += 128 * 4;
  int*   rank   = (int*)p;        p += (size_t)E * 4;
  int*   bucket = (int*)p;        p += (size_t)E * 4;
  p = (char*)(((uintptr_t)p + 255) & ~(uintptr_t)255);
  unsigned short* Wtg = (unsigned short*)p;  p += 128 * 128 * 2;
  p = (char*)(((uintptr_t)p + 255) & ~(uintptr_t)255);
  unsigned* hu  = (unsigned*)p;   p += (size_t)N * 64 * 4;
  float* vpart  = (float*)p;

  k_wt<<<64, 256, 0, stream>>>(W1, Wtg);

  // zero: deg + ssum (contiguous)
  hipMemsetAsync(d_ws, 0, (size_t)(2 * N) * sizeof(float), stream);

  k_front<<<NDEG + NGEMM, 256, 0, stream>>>(x, Wtg, dst, deg, rank, hu,
                                            N, E, NDEG, nChunks);

  k_scan1<<<NB_SCAN, 256, 0, stream>>>(deg, bsum, N);
  k_scan2<<<1, 128, 0, stream>>>(bsum, NB_SCAN, offs, N);
  k_scan3<<<NB_SCAN, 256, 0, stream>>>(deg, bsum, offs, dinv, N);

  k_fill<<<(E + 1023) / 1024, 256, 0, stream>>>(src, dst, rank, offs, dinv,
                                                bucket, ssum, E);

  k_agg<<<AGG_BLOCKS, 256, 0, stream>>>(hu, bucket, offs, dinv, ssum, b1, vpart, N);

  k_final<<<1, 1024, 0, stream>>>(vpart, AGG_BLOCKS, W2, b2, out, 1.0f / N);
}

// Round 7
// 375.987 us; speedup vs baseline: 1.1631x; 1.1631x over previous
//
#include <hip/hip_runtime.h>

#define D 128

typedef __attribute__((ext_vector_type(8))) short short8;
typedef __attribute__((ext_vector_type(4))) float f32x4;

// ---- bf16 pack helpers (round-to-nearest-even)
__device__ inline unsigned bfr(float f) {
  unsigned u = __float_as_uint(f);
  return (u + 0x7fffu + ((u >> 16) & 1u)) >> 16;
}
__device__ inline unsigned pack2(float lo, float hi) {
  return bfr(lo) | (bfr(hi) << 16);
}
__device__ inline float unpk_lo(unsigned v) { return __uint_as_float(v << 16); }
__device__ inline float unpk_hi(unsigned v) { return __uint_as_float(v & 0xffff0000u); }

// ---------------- W1 fp32 [k][n] -> bf16 transposed Wtg [n][k] (global, 32 KB)
__global__ __launch_bounds__(256) void k_wt(const float* __restrict__ W,
                                            unsigned short* __restrict__ Wtg) {
  int i = blockIdx.x * 256 + threadIdx.x;
  if (i < 128 * 128) {
    int k = i >> 7, n = i & 127;
    Wtg[n * 128 + k] = (unsigned short)bfr(W[k * 128 + n]);
  }
}

// ---------------- FUSED front: deg+rank (role A) || MFMA gemm h = x@W1 (role B)
__global__ __launch_bounds__(256) void k_front(
    const float* __restrict__ x, const unsigned short* __restrict__ Wtg,
    const int* __restrict__ dst, int* __restrict__ deg, int* __restrict__ rank,
    unsigned* __restrict__ hu, int M, int E, int NDEG, int nChunks) {
  __shared__ unsigned short xs[64 * 136];
  int b = blockIdx.x;
  int t = threadIdx.x;

  if (b < NDEG) {
    for (int c = b; c < nChunks; c += NDEG) {
      int i = c * 1024 + t * 4;
      if (i + 3 < E) {
        int4 d4 = *(const int4*)(dst + i);
        int4 r4;
        r4.x = atomicAdd(&deg[d4.x], 1);
        r4.y = atomicAdd(&deg[d4.y], 1);
        r4.z = atomicAdd(&deg[d4.z], 1);
        r4.w = atomicAdd(&deg[d4.w], 1);
        *(int4*)(rank + i) = r4;
      } else {
        for (int j = i; j < E; ++j) rank[j] = atomicAdd(&deg[dst[j]], 1);
      }
    }
    return;
  }

  int row0 = (b - NDEG) * 64;
  if (row0 >= M) return;

  for (int i = t; i < 2048; i += 256) {
    int r = i >> 5;
    int rg = row0 + r;
    int rc = rg < M ? rg : M - 1;
    float4 v = ((const float4*)x)[(size_t)rc * 32 + (i & 31)];
    *(uint2*)&xs[r * 136 + (i & 31) * 4] = make_uint2(pack2(v.x, v.y), pack2(v.z, v.w));
  }
  __syncthreads();

  int lane = t & 63;
  int wid = t >> 6;
  int l15 = lane & 15;
  int quad = lane >> 4;
  int mloc = wid * 16 + l15;

  f32x4 acc[8];
  #pragma unroll
  for (int ct = 0; ct < 8; ++ct) acc[ct] = (f32x4){0.f, 0.f, 0.f, 0.f};

  #pragma unroll
  for (int k0 = 0; k0 < 128; k0 += 32) {
    short8 af = *(const short8*)&xs[mloc * 136 + k0 + quad * 8];
    #pragma unroll
    for (int ct = 0; ct < 8; ++ct) {
      short8 bf = *(const short8*)(Wtg + (ct * 16 + l15) * 128 + k0 + quad * 8);
      acc[ct] = __builtin_amdgcn_mfma_f32_16x16x32_bf16(af, bf, acc[ct], 0, 0, 0);
    }
  }

  int rowbase = row0 + wid * 16 + quad * 4;
  #pragma unroll
  for (int ct = 0; ct < 8; ++ct) {
    #pragma unroll
    for (int r = 0; r < 4; ++r) {
      float v = acc[ct][r];
      float vp = __shfl_xor(v, 1, 64);
      int row = rowbase + r;
      if (!(lane & 1) && row < M)
        hu[(size_t)row * 64 + ct * 8 + (l15 >> 1)] = pack2(v, vp);
    }
  }
}

// ---------------- scan stage 1: per-block (1024 elems) sums
__global__ __launch_bounds__(256) void k_scan1(const int* __restrict__ deg,
                                               int* __restrict__ bsum, int N) {
  int t = threadIdx.x;
  int base = blockIdx.x * 1024;
  int s = 0;
  for (int i = t; i < 1024; i += 256) {
    int idx = base + i;
    if (idx < N) s += deg[idx];
  }
  __shared__ int red[256];
  red[t] = s;
  __syncthreads();
  for (int off = 128; off > 0; off >>= 1) {
    if (t < off) red[t] += red[t + off];
    __syncthreads();
  }
  if (t == 0) bsum[blockIdx.x] = red[0];
}

// ---------------- scan stage 3 (fused stage 2): each block re-scans bsum in LDS,
// then in-block exclusive scan -> offs; fused dinv
__global__ __launch_bounds__(256) void k_scan3(const int* __restrict__ deg,
                                               const int* __restrict__ bsum, int nb,
                                               int* __restrict__ offs,
                                               float* __restrict__ dinv, int N) {
  int t = threadIdx.x;
  __shared__ int sc2[128];
  if (t < 128) sc2[t] = (t < nb) ? bsum[t] : 0;
  __syncthreads();
  #pragma unroll
  for (int off = 1; off < 128; off <<= 1) {
    int x = 0;
    if (t < 128 && t >= off) x = sc2[t - off];
    __syncthreads();
    if (t < 128) sc2[t] += x;
    __syncthreads();
  }
  int bbase = (blockIdx.x == 0) ? 0 : sc2[blockIdx.x - 1];
  if (blockIdx.x == 0 && t == 0) offs[N] = sc2[nb - 1];  // total == E

  int base = blockIdx.x * 1024 + t * 4;
  int v[4];
  int s = 0;
  #pragma unroll
  for (int j = 0; j < 4; ++j) {
    int idx = base + j;
    v[j] = (idx < N) ? deg[idx] : 0;
    s += v[j];
  }
  __shared__ int sc[256];
  sc[t] = s;
  __syncthreads();
  for (int off = 1; off < 256; off <<= 1) {
    int x = (t >= off) ? sc[t - off] : 0;
    __syncthreads();
    sc[t] += x;
    __syncthreads();
  }
  int p = bbase + sc[t] - s;
  #pragma unroll
  for (int j = 0; j < 4; ++j) {
    int idx = base + j;
    if (idx < N) {
      offs[idx] = p;
      dinv[idx] = rsqrtf((float)v[j] + 1.0f);
      p += v[j];
    }
  }
}

// ---------------- fill: pure atomic-free CSR bucket write
__global__ __launch_bounds__(256) void k_fill(
    const int* __restrict__ src, const int* __restrict__ dst,
    const int* __restrict__ rank, const int* __restrict__ offs,
    int* __restrict__ bucket, int E) {
  int i = (blockIdx.x * 256 + threadIdx.x) * 4;
  if (i + 3 < E) {
    int4 s4 = *(const int4*)(src + i);
    int4 d4 = *(const int4*)(dst + i);
    int4 r4 = *(const int4*)(rank + i);
    bucket[offs[d4.x] + r4.x] = s4.x;
    bucket[offs[d4.y] + r4.y] = s4.y;
    bucket[offs[d4.z] + r4.z] = s4.z;
    bucket[offs[d4.w] + r4.w] = s4.w;
  } else {
    for (int j = i; j < E; ++j) bucket[offs[dst[j]] + rank[j]] = src[j];
  }
}

// ---------------- gather-aggregate + ReLU epilogue -> a1 (bf16 packed);
// lane 0 fires ssum[s] += dinv[r] atomics (hidden under gather)
__global__ __launch_bounds__(256) void k_agg(const unsigned* __restrict__ hu,
                                             const int* __restrict__ bucket,
                                             const int* __restrict__ offs,
                                             const float* __restrict__ dinv,
                                             float* __restrict__ ssum,
                                             const float* __restrict__ b1,
                                             unsigned* __restrict__ a1u, int N) {
  int lane = threadIdx.x & 63;
  int wid = threadIdx.x >> 6;
  int gwave = blockIdx.x * 4 + wid;
  int nwave = gridDim.x * 4;
  float2 bb = *(const float2*)(b1 + lane * 2);

  for (int r = gwave; r < N; r += nwave) {
    int beg = offs[r], end = offs[r + 1];
    float di = dinv[r];
    float ax = 0.f, ay = 0.f;
    int j = beg;
    for (; j + 4 <= end; j += 4) {
      int s0 = bucket[j], s1 = bucket[j + 1], s2 = bucket[j + 2], s3 = bucket[j + 3];
      float e0 = dinv[s0], e1 = dinv[s1], e2 = dinv[s2], e3 = dinv[s3];
      unsigned v0 = hu[(size_t)s0 * 64 + lane];
      unsigned v1 = hu[(size_t)s1 * 64 + lane];
      unsigned v2 = hu[(size_t)s2 * 64 + lane];
      unsigned v3 = hu[(size_t)s3 * 64 + lane];
      if (lane == 0) {
        unsafeAtomicAdd(&ssum[s0], di);
        unsafeAtomicAdd(&ssum[s1], di);
        unsafeAtomicAdd(&ssum[s2], di);
        unsafeAtomicAdd(&ssum[s3], di);
      }
      ax = fmaf(e0, unpk_lo(v0), ax);
      ay = fmaf(e0, unpk_hi(v0), ay);
      ax = fmaf(e1, unpk_lo(v1), ax);
      ay = fmaf(e1, unpk_hi(v1), ay);
      ax = fmaf(e2, unpk_lo(v2), ax);
      ay = fmaf(e2, unpk_hi(v2), ay);
      ax = fmaf(e3, unpk_lo(v3), ax);
      ay = fmaf(e3, unpk_hi(v3), ay);
    }
    for (; j < end; ++j) {
      int s = bucket[j];
      float e = dinv[s];
      unsigned v = hu[(size_t)s * 64 + lane];
      if (lane == 0) unsafeAtomicAdd(&ssum[s], di);
      ax = fmaf(e, unpk_lo(v), ax);
      ay = fmaf(e, unpk_hi(v), ay);
    }
    unsigned gr = hu[(size_t)r * 64 + lane];
    float hx = fmaxf(fmaf(di, fmaf(di, unpk_lo(gr), ax), bb.x), 0.f);
    float hy = fmaxf(fmaf(di, fmaf(di, unpk_hi(gr), ay), bb.y), 0.f);
    a1u[(size_t)r * 64 + lane] = pack2(hx, hy);
  }
}

// ---------------- weighted reduce: vpart[blk] = sum_r dinv[r]*(ssum[r]+dinv[r])*a1[r]
__global__ __launch_bounds__(256) void k_vred(const unsigned* __restrict__ a1u,
                                              const float* __restrict__ dinv,
                                              const float* __restrict__ ssum,
                                              float* __restrict__ vpart, int N) {
  int lane = threadIdx.x & 63;
  int wid = threadIdx.x >> 6;
  float vx = 0.f, vy = 0.f;
  for (int r = blockIdx.x * 4 + wid; r < N; r += gridDim.x * 4) {
    float di = dinv[r];
    float w = di * (ssum[r] + di);
    unsigned v = a1u[(size_t)r * 64 + lane];
    vx = fmaf(w, unpk_lo(v), vx);
    vy = fmaf(w, unpk_hi(v), vy);
  }
  __shared__ float2 red[256];
  red[threadIdx.x] = make_float2(vx, vy);
  __syncthreads();
  if (threadIdx.x < 64) {
    float2 a = red[threadIdx.x], b = red[threadIdx.x + 64];
    float2 c = red[threadIdx.x + 128], d = red[threadIdx.x + 192];
    float2 o = make_float2((a.x + b.x) + (c.x + d.x), (a.y + b.y) + (c.y + d.y));
    *(float2*)(vpart + (size_t)blockIdx.x * D + lane * 2) = o;
  }
}

// ---------------- final: v = sum partials; out = (1/N)*v@W2 + b2
__global__ __launch_bounds__(1024) void k_final(const float* __restrict__ vpart,
                                                int npart,
                                                const float* __restrict__ W2,
                                                const float* __restrict__ b2,
                                                float* __restrict__ out, float invN) {
  __shared__ float seg[8][128];
  __shared__ float vs[128];
  int t = threadIdx.x;
  int c = t & 127, sg = t >> 7;
  float s = 0.f;
  for (int b = sg; b < npart; b += 8) s += vpart[(size_t)b * D + c];
  seg[sg][c] = s;
  __syncthreads();
  if (t < 128) {
    float tot = 0.f;
    #pragma unroll
    for (int k = 0; k < 8; ++k) tot += seg[k][c];
    vs[c] = tot;
  }
  __syncthreads();
  if (t < 128) {
    float o = 0.f;
    for (int k = 0; k < 128; ++k) o = fmaf(vs[k], W2[k * D + c], o);
    out[c] = fmaf(o, invN, b2[c]);
  }
}

extern "C" void kernel_launch(void* const* d_in, const int* in_sizes, int n_in,
                              void* d_out, int out_size, void* d_ws, size_t ws_size,
                              hipStream_t stream) {
  const float* x  = (const float*)d_in[0];
  const int*   ei = (const int*)d_in[1];
  const float* W1 = (const float*)d_in[2];
  const float* b1 = (const float*)d_in[3];
  const float* W2 = (const float*)d_in[4];
  const float* b2 = (const float*)d_in[5];
  float* out = (float*)d_out;

  int N = in_sizes[0] / D;
  int E = in_sizes[1] / 2;
  const int* src = ei;
  const int* dst = ei + E;

  const int NB_SCAN = (N + 1023) / 1024;
  const int AGG_BLOCKS = 2048;
  const int VRED_BLOCKS = 256;
  const int nChunks = (E + 1023) / 1024;
  const int NDEG = (nChunks + 1) / 2;
  const int NGEMM = (N + 63) / 64;

  char* p = (char*)d_ws;
  int*   deg    = (int*)p;        p += (size_t)N * 4;
  float* ssum   = (float*)p;      p += (size_t)N * 4;
  float* dinv   = (float*)p;      p += (size_t)N * 4;
  int*   offs   = (int*)p;        p += (size_t)(N + 1) * 4;
  int*   bsum   = (int*)p;        p += 128 * 4;
  int*   rank   = (int*)p;        p += (size_t)E * 4;
  int*   bucket = (int*)p;        p += (size_t)E * 4;
  p = (char*)(((uintptr_t)p + 255) & ~(uintptr_t)255);
  unsigned short* Wtg = (unsigned short*)p;  p += 128 * 128 * 2;
  p = (char*)(((uintptr_t)p + 255) & ~(uintptr_t)255);
  unsigned* hu  = (unsigned*)p;   p += (size_t)N * 64 * 4;
  unsigned* a1u = (unsigned*)p;   p += (size_t)N * 64 * 4;
  float* vpart  = (float*)p;

  k_wt<<<64, 256, 0, stream>>>(W1, Wtg);

  // zero: deg + ssum (contiguous)
  hipMemsetAsync(d_ws, 0, (size_t)(2 * N) * sizeof(float), stream);

  k_front<<<NDEG + NGEMM, 256, 0, stream>>>(x, Wtg, dst, deg, rank, hu,
                                            N, E, NDEG, nChunks);

  k_scan1<<<NB_SCAN, 256, 0, stream>>>(deg, bsum, N);
  k_scan3<<<NB_SCAN, 256, 0, stream>>>(deg, bsum, NB_SCAN, offs, dinv, N);

  k_fill<<<(E + 1023) / 1024, 256, 0, stream>>>(src, dst, rank, offs, bucket, E);

  k_agg<<<AGG_BLOCKS, 256, 0, stream>>>(hu, bucket, offs, dinv, ssum, b1, a1u, N);

  k_vred<<<VRED_BLOCKS, 256, 0, stream>>>(a1u, dinv, ssum, vpart, N);

  k_final<<<1, 1024, 0, stream>>>(vpart, VRED_BLOCKS, W2, b2, out, 1.0f / N);
}